// Round 9
// baseline (222.653 us; speedup 1.0000x reference)
//
#include <hip/hip_runtime.h>

#define NS 5      // symbols
#define NW 33     // subcarriers
#define NA 16     // antennas
#define SW 165    // NS*NW
#define GM 5      // matrices per block (one wave)
#define TPM 11    // threads per matrix
#define CPT 3     // columns per thread
#define THREADS 64
#define ACTIVE (GM*TPM)   // 55

// One wave per workgroup: __syncthreads has no cross-wave lockstep (R8 showed
// barrier drain, not LDS size, limits the 256-thread variant). Do NOT add a
// min-waves launch-bounds arg (R5/R7: register caps -> scratch spill).
__global__ __launch_bounds__(THREADS) void autocorr_kernel(
    const float* __restrict__ x_real, const float* __restrict__ x_imag,
    const float* __restrict__ Fsym_re, const float* __restrict__ Fsym_im,
    const float* __restrict__ Fsub_re, const float* __restrict__ Fsub_im,
    float* __restrict__ out, int NM, int write_complex)
{
    __shared__ float2 sFsym[NS * NS];   // [s][t]
    __shared__ float2 sFsub[NW * NW];   // [w][v] row-major
    __shared__ float2 buf[GM][SW];      // x [t][w] -> T1 col-major [w][s] -> T2 col-major [v][p<3]

    const int tid = threadIdx.x;
    const int M0 = blockIdx.x * GM;

    // ---- stage F matrices into LDS (L2-hot: 8.7 KB re-read per block) ----
    for (int i = tid; i < NW * NW; i += THREADS)
        sFsub[i] = make_float2(Fsub_re[i], Fsub_im[i]);
    if (tid < NS * NS) sFsym[tid] = make_float2(Fsym_re[tid], Fsym_im[tid]);

    // ---- stage x into LDS (coalesced scalar dwords across lanes) ----
    for (int e = tid; e < GM * SW; e += THREADS) {
        int g = e / SW, r = e % SW;
        int M = M0 + g;
        if (M < NM) {
            int t = r / NW, w = r % NW;
            int n = M >> 4, a = M & 15;
            int off = ((n * NS + t) * NA + a) * NW + w;
            buf[g][r] = make_float2(x_real[off], x_imag[off]);
        } else {
            buf[g][r] = make_float2(0.f, 0.f);
        }
    }
    __syncthreads();   // intra-wave only

    const int g = tid / TPM;
    const int j = tid - g * TPM;
    const bool act = (tid < ACTIVE);
    const int M = M0 + g;
    const int c0 = 3 * j;

    // ---- read my x columns into registers ----
    float2 xr[NS][CPT];
    if (act) {
#pragma unroll
        for (int t = 0; t < NS; ++t)
#pragma unroll
            for (int k = 0; k < CPT; ++k)
                xr[t][k] = buf[g][t * NW + c0 + k];
    }
    __syncthreads();   // x reads done before T1 overwrites buf

    // ---- Stage A: T1[s][w] = sum_t Fsym[s][t]*x[t][w] ----
    if (act) {
        float2 A[NS][CPT];
#pragma unroll
        for (int s = 0; s < NS; ++s)
#pragma unroll
            for (int k = 0; k < CPT; ++k) A[s][k] = make_float2(0.f, 0.f);
#pragma unroll
        for (int t = 0; t < NS; ++t) {
#pragma unroll
            for (int s = 0; s < NS; ++s) {
                float2 f = sFsym[s * NS + t];   // broadcast
#pragma unroll
                for (int k = 0; k < CPT; ++k) {
                    A[s][k].x = fmaf(f.x, xr[t][k].x, A[s][k].x);
                    A[s][k].x = fmaf(-f.y, xr[t][k].y, A[s][k].x);
                    A[s][k].y = fmaf(f.x, xr[t][k].y, A[s][k].y);
                    A[s][k].y = fmaf(f.y, xr[t][k].x, A[s][k].y);
                }
            }
        }
        // T1 col-major: buf[g][w*NS + s], w = c0+k (15 consecutive float2)
#pragma unroll
        for (int k = 0; k < CPT; ++k)
#pragma unroll
            for (int s = 0; s < NS; ++s)
                buf[g][(c0 + k) * NS + s] = A[s][k];
    }
    __syncthreads();   // T1 ready

    // ---- Stage B: X[s][v] = sum_w T1[s][w]*Fsub[w][v], v = c0+k ----
    float2 X[NS][CPT];
#pragma unroll
    for (int s = 0; s < NS; ++s)
#pragma unroll
        for (int k = 0; k < CPT; ++k) X[s][k] = make_float2(0.f, 0.f);
    if (act) {
        const float2* bp = buf[g];
#pragma unroll 3
        for (int w = 0; w < NW; ++w) {
            float2 tc[NS];
#pragma unroll
            for (int s = 0; s < NS; ++s) tc[s] = bp[w * NS + s];   // broadcast within matrix
            float2 fv[CPT];
#pragma unroll
            for (int k = 0; k < CPT; ++k) fv[k] = sFsub[w * NW + c0 + k];
#pragma unroll
            for (int s = 0; s < NS; ++s)
#pragma unroll
                for (int k = 0; k < CPT; ++k) {
                    X[s][k].x = fmaf(tc[s].x, fv[k].x, X[s][k].x);
                    X[s][k].x = fmaf(-tc[s].y, fv[k].y, X[s][k].x);
                    X[s][k].y = fmaf(tc[s].x, fv[k].y, X[s][k].y);
                    X[s][k].y = fmaf(tc[s].y, fv[k].x, X[s][k].y);
                }
        }
    }
    __syncthreads();   // T1 reads done before T2 overwrites buf

    // ---- P = |X|^2; Stage D (Hermitian: p=0..2): T2[p][v] = sum_s conj(Fsym[s][p])*P[s][v] ----
    if (act) {
        float P[NS][CPT];
#pragma unroll
        for (int s = 0; s < NS; ++s)
#pragma unroll
            for (int k = 0; k < CPT; ++k)
                P[s][k] = X[s][k].x * X[s][k].x + X[s][k].y * X[s][k].y;

        float2 T2[3][CPT];
#pragma unroll
        for (int p = 0; p < 3; ++p)
#pragma unroll
            for (int k = 0; k < CPT; ++k) T2[p][k] = make_float2(0.f, 0.f);
#pragma unroll
        for (int s = 0; s < NS; ++s) {
#pragma unroll
            for (int p = 0; p < 3; ++p) {
                float2 f = sFsym[s * NS + p];
#pragma unroll
                for (int k = 0; k < CPT; ++k) {
                    T2[p][k].x = fmaf(f.x, P[s][k], T2[p][k].x);
                    T2[p][k].y = fmaf(-f.y, P[s][k], T2[p][k].y);
                }
            }
        }
        // T2 col-major, 3 rows: buf[g][v*3 + p], v = c0+k (9 consecutive float2)
#pragma unroll
        for (int k = 0; k < CPT; ++k)
#pragma unroll
            for (int p = 0; p < 3; ++p)
                buf[g][(c0 + k) * 3 + p] = T2[p][k];
    }
    __syncthreads();   // T2 ready

    // ---- Stage E: Y[p][q] = sum_v T2[p][v]*conj(Fsub[q][v]), q = c0+k ----
    if (act) {
        const float2* bp = buf[g];
        if (!write_complex) {
            // Real part only (harness output is float32 = Re(Y)).
            float Yr[3][CPT];
#pragma unroll
            for (int p = 0; p < 3; ++p)
#pragma unroll
                for (int k = 0; k < CPT; ++k) Yr[p][k] = 0.f;
#pragma unroll 3
            for (int v = 0; v < NW; ++v) {
                float2 tc[3];
#pragma unroll
                for (int p = 0; p < 3; ++p) tc[p] = bp[v * 3 + p];   // broadcast within matrix
                float2 fw[CPT];
#pragma unroll
                for (int k = 0; k < CPT; ++k) fw[k] = sFsub[(c0 + k) * NW + v]; // = Fsub[q][v]
#pragma unroll
                for (int p = 0; p < 3; ++p)
#pragma unroll
                    for (int k = 0; k < CPT; ++k) {
                        // Re(tc * conj(fw)) = tc.x*fw.x + tc.y*fw.y
                        Yr[p][k] = fmaf(tc[p].x, fw[k].x, Yr[p][k]);
                        Yr[p][k] = fmaf(tc[p].y, fw[k].y, Yr[p][k]);
                    }
            }
            if (M < NM) {
                int n = M >> 4, a = M & 15;
                int obase = ((n * NS) * NA + a) * NW;
#pragma unroll
                for (int p = 0; p < 3; ++p) {
                    const int pp = (NS - p) % NS;   // 0,4,3
#pragma unroll
                    for (int k = 0; k < CPT; ++k) {
                        const int q = c0 + k;
                        const int qq = (NW - q) % NW;
                        out[obase + p * (NA * NW) + q] = Yr[p][k];
                        out[obase + pp * (NA * NW) + qq] = Yr[p][k];
                    }
                }
            }
        } else {
            // Fallback: full complex output (not expected on this harness).
            float2 Y[3][CPT];
#pragma unroll
            for (int p = 0; p < 3; ++p)
#pragma unroll
                for (int k = 0; k < CPT; ++k) Y[p][k] = make_float2(0.f, 0.f);
            for (int v = 0; v < NW; ++v) {
                float2 tc[3];
#pragma unroll
                for (int p = 0; p < 3; ++p) tc[p] = bp[v * 3 + p];
                float2 fw[CPT];
#pragma unroll
                for (int k = 0; k < CPT; ++k) fw[k] = sFsub[(c0 + k) * NW + v];
#pragma unroll
                for (int p = 0; p < 3; ++p)
#pragma unroll
                    for (int k = 0; k < CPT; ++k) {
                        Y[p][k].x = fmaf(tc[p].x, fw[k].x, Y[p][k].x);
                        Y[p][k].x = fmaf(tc[p].y, fw[k].y, Y[p][k].x);
                        Y[p][k].y = fmaf(tc[p].y, fw[k].x, Y[p][k].y);
                        Y[p][k].y = fmaf(-tc[p].x, fw[k].y, Y[p][k].y);
                    }
            }
            if (M < NM) {
                int n = M >> 4, a = M & 15;
#pragma unroll
                for (int p = 0; p < 3; ++p) {
                    const int pp = (NS - p) % NS;
#pragma unroll
                    for (int k = 0; k < CPT; ++k) {
                        const int q = c0 + k;
                        const int qq = (NW - q) % NW;
                        ((float2*)out)[((n * NS + p) * NA + a) * NW + q] = Y[p][k];
                        ((float2*)out)[((n * NS + pp) * NA + a) * NW + qq] =
                            make_float2(Y[p][k].x, -Y[p][k].y);
                    }
                }
            }
        }
    }
}

extern "C" void kernel_launch(void* const* d_in, const int* in_sizes, int n_in,
                              void* d_out, int out_size, void* d_ws, size_t ws_size,
                              hipStream_t stream) {
    const float* x_real  = (const float*)d_in[0];
    const float* x_imag  = (const float*)d_in[1];
    const float* Fsym_re = (const float*)d_in[2];
    const float* Fsym_im = (const float*)d_in[3];
    const float* Fsub_re = (const float*)d_in[4];
    const float* Fsub_im = (const float*)d_in[5];

    const int NM = in_sizes[0] / SW;
    const long long n_cplx = (long long)in_sizes[0];
    const int write_complex = ((long long)out_size >= 2 * n_cplx) ? 1 : 0;

    const int blocks = (NM + GM - 1) / GM;

    autocorr_kernel<<<blocks, THREADS, 0, stream>>>(
        x_real, x_imag, Fsym_re, Fsym_im, Fsub_re, Fsub_im,
        (float*)d_out, NM, write_complex);
}

// Round 10
// 191.556 us; speedup vs baseline: 1.1623x; 1.1623x over previous
//
#include <hip/hip_runtime.h>

#define NS 5      // symbols
#define NW 33     // subcarriers
#define NA 16     // antennas
#define SW 165    // NS*NW
#define GM 23     // matrices per block
#define TPM 11    // threads per matrix
#define CPT 3     // columns per thread
#define THREADS 256
#define ACTIVE (GM*TPM)   // 253

// Lessons baked in: 256 threads (R9: 64T starves CUs), no min-waves bound
// (R5/R7: register cap -> spill), sFsub as LDS table (R8: wtab index VALU tax),
// A/B fused (R7 launch-1 proved correctness; kills 2 barriers + T1 round-trip).
__global__ __launch_bounds__(THREADS, 4) void autocorr_kernel(
    const float* __restrict__ x_real, const float* __restrict__ x_imag,
    const float* __restrict__ Fsym_re, const float* __restrict__ Fsym_im,
    const float* __restrict__ Fsub_re, const float* __restrict__ Fsub_im,
    float* __restrict__ out, int NM, int write_complex)
{
    __shared__ float2 sFsym[NS * NS];   // [s][t]
    __shared__ float2 sFsub[NW * NW];   // [w][v] row-major
    __shared__ float2 buf[GM][SW];      // x col-major [w][t] -> T2 col-major [v][p<3]

    const int tid = threadIdx.x;
    const int M0 = blockIdx.x * GM;

    // ---- stage F matrices into LDS ----
    for (int i = tid; i < NW * NW; i += THREADS)
        sFsub[i] = make_float2(Fsub_re[i], Fsub_im[i]);
    if (tid < NS * NS) sFsym[tid] = make_float2(Fsym_re[tid], Fsym_im[tid]);

    // ---- stage x into LDS col-major: buf[g][w*NS + t] (coalesced global reads) ----
    for (int e = tid; e < GM * SW; e += THREADS) {
        int g = e / SW, r = e % SW;
        int t = r / NW, w = r % NW;
        int M = M0 + g;
        float2 val = make_float2(0.f, 0.f);
        if (M < NM) {
            int n = M >> 4, a = M & 15;
            int off = ((n * NS + t) * NA + a) * NW + w;
            val = make_float2(x_real[off], x_imag[off]);
        }
        buf[g][w * NS + t] = val;
    }
    __syncthreads();   // barrier 1: LDS staged

    const int g = tid / TPM;
    const int j = tid - g * TPM;
    const bool act = (tid < ACTIVE);
    const int M = M0 + g;
    const int c0 = 3 * j;

    // ---- Fused A+B: V[t][k] = sum_w x[t][w] * Fsub[w][c0+k] ----
    float2 V[NS][CPT];
#pragma unroll
    for (int t = 0; t < NS; ++t)
#pragma unroll
        for (int k = 0; k < CPT; ++k) V[t][k] = make_float2(0.f, 0.f);
    if (act) {
        const float2* bp = buf[g];
#pragma unroll 3
        for (int w = 0; w < NW; ++w) {
            float2 xc[NS];
#pragma unroll
            for (int t = 0; t < NS; ++t) xc[t] = bp[w * NS + t];   // 5 consecutive float2
            float2 fv[CPT];
#pragma unroll
            for (int k = 0; k < CPT; ++k) fv[k] = sFsub[w * NW + c0 + k];
#pragma unroll
            for (int t = 0; t < NS; ++t)
#pragma unroll
                for (int k = 0; k < CPT; ++k) {
                    V[t][k].x = fmaf(xc[t].x, fv[k].x, V[t][k].x);
                    V[t][k].x = fmaf(-xc[t].y, fv[k].y, V[t][k].x);
                    V[t][k].y = fmaf(xc[t].x, fv[k].y, V[t][k].y);
                    V[t][k].y = fmaf(xc[t].y, fv[k].x, V[t][k].y);
                }
        }
    }

    // ---- X = F_sym*V (thread-local); P = |X|^2; Stage D (Hermitian p<3) -> T2 ----
    float2 T2[3][CPT];
#pragma unroll
    for (int p = 0; p < 3; ++p)
#pragma unroll
        for (int k = 0; k < CPT; ++k) T2[p][k] = make_float2(0.f, 0.f);
    if (act) {
#pragma unroll
        for (int s = 0; s < NS; ++s) {
            float2 X[CPT];
#pragma unroll
            for (int k = 0; k < CPT; ++k) X[k] = make_float2(0.f, 0.f);
#pragma unroll
            for (int t = 0; t < NS; ++t) {
                float2 f = sFsym[s * NS + t];   // broadcast
#pragma unroll
                for (int k = 0; k < CPT; ++k) {
                    X[k].x = fmaf(f.x, V[t][k].x, X[k].x);
                    X[k].x = fmaf(-f.y, V[t][k].y, X[k].x);
                    X[k].y = fmaf(f.x, V[t][k].y, X[k].y);
                    X[k].y = fmaf(f.y, V[t][k].x, X[k].y);
                }
            }
            float P[CPT];
#pragma unroll
            for (int k = 0; k < CPT; ++k)
                P[k] = X[k].x * X[k].x + X[k].y * X[k].y;
#pragma unroll
            for (int p = 0; p < 3; ++p) {
                float2 f = sFsym[s * NS + p];   // conj in MAC
#pragma unroll
                for (int k = 0; k < CPT; ++k) {
                    T2[p][k].x = fmaf(f.x, P[k], T2[p][k].x);
                    T2[p][k].y = fmaf(-f.y, P[k], T2[p][k].y);
                }
            }
        }
    }
    __syncthreads();   // barrier 2: all x reads done before T2 overwrites buf

    if (act) {
        // T2 col-major, 3 rows: buf[g][v*3 + p], v = c0+k (9 consecutive float2)
#pragma unroll
        for (int k = 0; k < CPT; ++k)
#pragma unroll
            for (int p = 0; p < 3; ++p)
                buf[g][(c0 + k) * 3 + p] = T2[p][k];
    }
    __syncthreads();   // barrier 3: T2 ready

    // ---- Stage E: Y[p][q] = sum_v T2[p][v]*conj(Fsub[q][v]), q = c0+k ----
    if (act) {
        const float2* bp = buf[g];
        if (!write_complex) {
            // Real part only (harness output is float32 = Re(Y)).
            float Yr[3][CPT];
#pragma unroll
            for (int p = 0; p < 3; ++p)
#pragma unroll
                for (int k = 0; k < CPT; ++k) Yr[p][k] = 0.f;
#pragma unroll 3
            for (int v = 0; v < NW; ++v) {
                float2 tc[3];
#pragma unroll
                for (int p = 0; p < 3; ++p) tc[p] = bp[v * 3 + p];   // broadcast within matrix
                float2 fw[CPT];
#pragma unroll
                for (int k = 0; k < CPT; ++k) fw[k] = sFsub[(c0 + k) * NW + v]; // = Fsub[q][v]
#pragma unroll
                for (int p = 0; p < 3; ++p)
#pragma unroll
                    for (int k = 0; k < CPT; ++k) {
                        // Re(tc * conj(fw)) = tc.x*fw.x + tc.y*fw.y
                        Yr[p][k] = fmaf(tc[p].x, fw[k].x, Yr[p][k]);
                        Yr[p][k] = fmaf(tc[p].y, fw[k].y, Yr[p][k]);
                    }
            }
            if (M < NM) {
                int n = M >> 4, a = M & 15;
                int obase = ((n * NS) * NA + a) * NW;
#pragma unroll
                for (int p = 0; p < 3; ++p) {
                    const int pp = (NS - p) % NS;   // 0,4,3
#pragma unroll
                    for (int k = 0; k < CPT; ++k) {
                        const int q = c0 + k;
                        const int qq = (NW - q) % NW;
                        out[obase + p * (NA * NW) + q] = Yr[p][k];
                        out[obase + pp * (NA * NW) + qq] = Yr[p][k];
                    }
                }
            }
        } else {
            // Fallback: full complex output (not expected on this harness).
            float2 Y[3][CPT];
#pragma unroll
            for (int p = 0; p < 3; ++p)
#pragma unroll
                for (int k = 0; k < CPT; ++k) Y[p][k] = make_float2(0.f, 0.f);
            for (int v = 0; v < NW; ++v) {
                float2 tc[3];
#pragma unroll
                for (int p = 0; p < 3; ++p) tc[p] = bp[v * 3 + p];
                float2 fw[CPT];
#pragma unroll
                for (int k = 0; k < CPT; ++k) fw[k] = sFsub[(c0 + k) * NW + v];
#pragma unroll
                for (int p = 0; p < 3; ++p)
#pragma unroll
                    for (int k = 0; k < CPT; ++k) {
                        Y[p][k].x = fmaf(tc[p].x, fw[k].x, Y[p][k].x);
                        Y[p][k].x = fmaf(tc[p].y, fw[k].y, Y[p][k].x);
                        Y[p][k].y = fmaf(tc[p].y, fw[k].x, Y[p][k].y);
                        Y[p][k].y = fmaf(-tc[p].x, fw[k].y, Y[p][k].y);
                    }
            }
            if (M < NM) {
                int n = M >> 4, a = M & 15;
#pragma unroll
                for (int p = 0; p < 3; ++p) {
                    const int pp = (NS - p) % NS;
#pragma unroll
                    for (int k = 0; k < CPT; ++k) {
                        const int q = c0 + k;
                        const int qq = (NW - q) % NW;
                        ((float2*)out)[((n * NS + p) * NA + a) * NW + q] = Y[p][k];
                        ((float2*)out)[((n * NS + pp) * NA + a) * NW + qq] =
                            make_float2(Y[p][k].x, -Y[p][k].y);
                    }
                }
            }
        }
    }
}

extern "C" void kernel_launch(void* const* d_in, const int* in_sizes, int n_in,
                              void* d_out, int out_size, void* d_ws, size_t ws_size,
                              hipStream_t stream) {
    const float* x_real  = (const float*)d_in[0];
    const float* x_imag  = (const float*)d_in[1];
    const float* Fsym_re = (const float*)d_in[2];
    const float* Fsym_im = (const float*)d_in[3];
    const float* Fsub_re = (const float*)d_in[4];
    const float* Fsub_im = (const float*)d_in[5];

    const int NM = in_sizes[0] / SW;
    const long long n_cplx = (long long)in_sizes[0];
    const int write_complex = ((long long)out_size >= 2 * n_cplx) ? 1 : 0;

    const int blocks = (NM + GM - 1) / GM;

    autocorr_kernel<<<blocks, THREADS, 0, stream>>>(
        x_real, x_imag, Fsym_re, Fsym_im, Fsub_re, Fsub_im,
        (float*)d_out, NM, write_complex);
}